// Round 10
// baseline (648.966 us; speedup 1.0000x reference)
//
#include <hip/hip_runtime.h>
#include <math.h>

typedef _Float16 half_t;
typedef _Float16 half8_t __attribute__((ext_vector_type(8)));
typedef float float4_t __attribute__((ext_vector_type(4)));

#define T_ 64
#define B_ 256
#define D_ 16
#define S_ 64
#define H_ 128
#define O_ 8
#define NSTEP 63
#define NT 1024

// ws layout (halves):
//   [0, 131072)        Wf3 row-major [1024][128]
//   [131072, 139264)   Wf1 fragment-major: [g<8][n<128][i<8], k = (g>>2)*32 + (g&3)*8 + i
//   [139264, 155648)   Wf2 fragment-major: [g<16][n<128][i<8], same k map
#define W3_OFF 0
#define W1_OFF 131072
#define W2_OFF 139264
#define WS_HALVES 155648

#define MFMA16(a, b, c) __builtin_amdgcn_mfma_f32_16x16x32_f16(a, b, c, 0, 0, 0)

// DPP 16-lane butterfly add (VALU, replaces ds_bpermute-based __shfl_xor)
#if __has_builtin(__builtin_amdgcn_mov_dpp)
#define DPP_ADD(x, ctrl) \
  ((x) + __int_as_float(__builtin_amdgcn_mov_dpp(__float_as_int(x), (ctrl), 0xF, 0xF, true)))
#else
#define DPP_ADD(x, ctrl) ((x) + __shfl_xor((x), (ctrl) == 0xB1 ? 1 : (ctrl) == 0x4E ? 2 : (ctrl) == 0x141 ? 4 : 8))
#endif

// AE[j] = coefficients on k[0..j] producing the NEXT stage input (j<5) or B_SOL (j==5)
__device__ constexpr float AE[6][6] = {
  {0.161f, 0.f, 0.f, 0.f, 0.f, 0.f},
  {-0.008480655492356989f, 0.335480655492357f, 0.f, 0.f, 0.f, 0.f},
  {2.8971530571054935f, -6.359448489975075f, 4.3622954328695815f, 0.f, 0.f, 0.f},
  {5.325864828439257f, -11.748883564062828f, 7.4955393428898365f, -0.09249506636175525f, 0.f, 0.f},
  {5.86145544294642f, -12.92096931784711f, 8.159367898576159f, -0.071584973281401f, -0.028269050394068383f, 0.f},
  {0.09646076681806523f, 0.01f, 0.4798896504144996f, 1.379008574103742f, -3.290069515436081f, 2.324710524099774f}
};
__device__ constexpr float CCn[6] = {0.f, 0.161f, 0.327f, 0.9f, 0.9800255409045097f, 1.f};

__device__ __forceinline__ float softplus_f(float x) {
  return fmaxf(x, 0.f) + __logf(1.f + __expf(-fabsf(x)));
}
__device__ __forceinline__ float tanh_f(float x) {
  float xc = fminf(fmaxf(x, -12.f), 12.f);
  float e = __expf(2.f * xc);
  return (e - 1.f) * __builtin_amdgcn_rcpf(e + 1.f);
}

// ---------------- prologue: fp32 -> fp16 weight conversion ----------------
__global__ __launch_bounds__(256) void convert_kernel(
    const float* __restrict__ Wf1, const float* __restrict__ Wf2,
    const float* __restrict__ Wf3, half_t* __restrict__ wsh)
{
  int qi = blockIdx.x * 256 + threadIdx.x;
  if (qi < W1_OFF) {
    wsh[qi] = (half_t)Wf3[qi];
  } else if (qi < W2_OFF) {
    int rem = qi - W1_OFF;
    int g = rem >> 10, n = (rem >> 3) & 127, i = rem & 7;
    int k = (g >> 2) * 32 + (g & 3) * 8 + i;
    wsh[qi] = (half_t)Wf1[n * S_ + k];
  } else if (qi < WS_HALVES) {
    int rem = qi - W2_OFF;
    int g = rem >> 10, n = (rem >> 3) & 127, i = rem & 7;
    int k = (g >> 2) * 32 + (g & 3) * 8 + i;
    wsh[qi] = (half_t)Wf2[n * H_ + k];
  }
}

// ---------------- main kernel ----------------
// 16 waves (4/SIMD). Per stage: [h1: waves 0-7] B1 [h2: waves 8-15; proj wave 0 @ j==0]
// B2 [G3: all 16 waves, 4 tiles each] B3. Wf3 fragments persist in AGPRs (64/wave),
// Wf1 fragments persist in h1-wave registers (8), Wf2 re-read from LDS each stage
// (anti-LICM; latency hidden in phase 1). Epilogue: DPP butterfly + wave-uniform RK.
__global__ void __launch_bounds__(NT) __attribute__((amdgpu_waves_per_eu(4, 4)))
cde_kernel_mfma(
    const float* __restrict__ ts,
    const float* __restrict__ coeff_d,
    const float* __restrict__ coeff_c,
    const float* __restrict__ coeff_b,
    const float* __restrict__ coeff_a,
    const float* __restrict__ Wi1, const float* __restrict__ bi1,
    const float* __restrict__ Wi2, const float* __restrict__ bi2,
    const float* __restrict__ bf1, const float* __restrict__ bf2,
    const float* __restrict__ bf3,
    const float* __restrict__ Wr, const float* __restrict__ br,
    const half_t* __restrict__ wsh,
    float* __restrict__ out)
{
  __shared__ __align__(16) half_t sW2L[16384];   // 32 KB, fragment-major
  __shared__ __align__(16) half_t syj_h[S_];
  __shared__ __align__(16) half_t sh1h[H_];
  __shared__ __align__(16) half_t sh2h[H_];
  __shared__ float syf[S_];
  __shared__ float skr[5][S_];
  __shared__ float sbf1[H_], sbf2[H_];
  __shared__ float sWr[O_ * S_];
  __shared__ float sbr[O_];
  __shared__ float sx0[D_];
  __shared__ float sini[H_];
  __shared__ float shs[T_];

  const int tid = threadIdx.x;
  const int b = blockIdx.x;
  const int w = tid >> 6;          // wave 0..15
  const int lane = tid & 63;
  const int q = lane >> 4;         // 16-lane row 0..3
  const int c = lane & 15;         // fragment column

  const bool isH1 = (w < 8);
  const int nO = 16 * (isH1 ? w : (w - 8)) + c;

  // ---- persistent Wf3 fragments (64 regs, AGPR-resident) ----
  half8_t bW3[4][4];
  #pragma unroll
  for (int tt = 0; tt < 4; ++tt) {
    const int r = 16 * (4 * w + tt) + c;
    #pragma unroll
    for (int ks = 0; ks < 4; ++ks)
      bW3[tt][ks] = *(const half8_t*)(wsh + W3_OFF + (size_t)r * H_ + ks * 32 + q * 8);
  }
  const int sE = 4 * w + q;
  const float bf3E = bf3[16 * sE + c];

  // ---- persistent Wf1 fragments on h1 waves (8 regs, from global, fragment-major) ----
  half8_t w1a = {}, w1b = {};
  if (isH1) {
    w1a = *(const half8_t*)(wsh + W1_OFF + (q * 128 + nO) * 8);
    w1b = *(const half8_t*)(wsh + W1_OFF + ((q + 4) * 128 + nO) * 8);
  }

  // ---- one-time staging ----
  {
    const float4* s2 = (const float4*)(wsh + W2_OFF);
    float4* d2 = (float4*)sW2L;
    for (int i = tid; i < 2048; i += NT) d2[i] = s2[i];
  }
  if (tid < O_ * S_) sWr[tid] = Wr[tid];
  if (tid < O_) sbr[tid] = br[tid];
  if (tid < D_) sx0[tid] = coeff_a[(size_t)b * NSTEP * D_ + tid];
  if (tid < NSTEP) shs[tid] = ts[tid + 1] - ts[tid];
  if (tid < H_) { sbf1[tid] = bf1[tid]; sbf2[tid] = bf2[tid]; }
  __syncthreads();

  // ---- y0 = softplus(x0 @ Wi1^T + bi1) @ Wi2^T + bi2 (fp32, once) ----
  if (tid < H_) {
    float acc = bi1[tid];
    #pragma unroll
    for (int d = 0; d < D_; ++d) acc += sx0[d] * Wi1[tid * D_ + d];
    sini[tid] = softplus_f(acc);
  }
  __syncthreads();
  if (tid < S_) {
    float acc = bi2[tid];
    for (int h = 0; h < H_; ++h) acc += sini[h] * Wi2[tid * H_ + h];
    syf[tid] = acc;
  }
  __syncthreads();

  // y state: wave-uniform per 16-lane row (all lanes of row q track y[sE])
  float yr = syf[sE];
  if (c == 0) syj_h[sE] = (half_t)yr;
  __syncthreads();

  const float4_t Zv = {0.f, 0.f, 0.f, 0.f};
  const char* sW2b = (const char*)sW2L;

  // ---- time loop ----
  for (int t = 0; t < NSTEP; ++t) {
    const float hstep = shs[t];
    const size_t cidx = ((size_t)b * NSTEP + t) * D_ + c;
    const float cbv = coeff_b[cidx];
    const float ccv = coeff_c[cidx];
    const float cdv = coeff_d[cidx];

    #pragma unroll
    for (int j = 0; j < 6; ++j) {
      half8_t wf0, wf1, wf2, wf3;
      // ---- phase 1: h1 (waves 0-7, persistent W1 regs); h2 waves prefetch W2 ----
      if (isH1) {
        const half8_t* ap = (const half8_t*)syj_h;
        half8_t a0 = ap[q];
        half8_t a1 = ap[4 + q];
        float4_t acc = MFMA16(a0, w1a, Zv);
        acc = MFMA16(a1, w1b, acc);
        if (q == 0) sh1h[nO] = (half_t)softplus_f(acc[0] + sbf1[nO]);
      } else {
        uint32_t o2 = (uint32_t)((q * 128 + nO) * 16);
        asm volatile("" : "+v"(o2));
        wf0 = *(const half8_t*)(sW2b + o2);
        wf1 = *(const half8_t*)(sW2b + o2 + 8192);
        wf2 = *(const half8_t*)(sW2b + o2 + 16384);
        wf3 = *(const half8_t*)(sW2b + o2 + 24576);
      }
      __syncthreads();   // B1

      // ---- phase 2: h2 (waves 8-15); out-projection on wave 0 (idle) at j==0 ----
      if (!isH1) {
        const half8_t* ap = (const half8_t*)sh1h;
        half8_t a0 = ap[q], a1 = ap[4 + q], a2 = ap[8 + q], a3 = ap[12 + q];
        float4_t acc = MFMA16(a0, wf0, Zv);
        acc = MFMA16(a1, wf1, acc);
        acc = MFMA16(a2, wf2, acc);
        acc = MFMA16(a3, wf3, acc);
        if (q == 0) sh2h[nO] = (half_t)softplus_f(acc[0] + sbf2[nO]);
      } else if (w == 0 && j == 0) {
        const int oo = lane >> 3, kc = lane & 7;
        float a = 0.f;
        #pragma unroll
        for (int i = 0; i < 8; ++i) a += syf[kc * 8 + i] * sWr[oo * S_ + kc * 8 + i];
        a += __shfl_down(a, 4, 8);
        a += __shfl_down(a, 2, 8);
        a += __shfl_down(a, 1, 8);
        if (kc == 0) out[((size_t)b * T_ + t) * O_ + oo] = a + sbr[oo];
      }
      __syncthreads();   // B2

      // ---- phase 3: G3 (all 16 waves) + DPP reduce + wave-uniform RK update ----
      {
        // hoist skr reads above the MFMA burst (latency hidden); broadcast reads
        float kprev[5];
        #pragma unroll
        for (int m = 0; m < 5; ++m) kprev[m] = (m < j) ? skr[m][sE] : 0.f;

        const half8_t* ap = (const half8_t*)sh2h;
        half8_t a0 = ap[q], a1 = ap[4 + q], a2 = ap[8 + q], a3 = ap[12 + q];
        float4_t acc3[4];
        #pragma unroll
        for (int tt = 0; tt < 4; ++tt) acc3[tt] = MFMA16(a0, bW3[tt][0], Zv);
        #pragma unroll
        for (int tt = 0; tt < 4; ++tt) acc3[tt] = MFMA16(a1, bW3[tt][1], acc3[tt]);
        #pragma unroll
        for (int tt = 0; tt < 4; ++tt) acc3[tt] = MFMA16(a2, bW3[tt][2], acc3[tt]);
        #pragma unroll
        for (int tt = 0; tt < 4; ++tt) acc3[tt] = MFMA16(a3, bW3[tt][3], acc3[tt]);

        const float s01 = (q & 1) ? acc3[1][0] : acc3[0][0];
        const float s23 = (q & 1) ? acc3[3][0] : acc3[2][0];
        const float v = (q & 2) ? s23 : s01;

        const float frac = CCn[j] * hstep;
        const float dx = cbv + frac * (2.f * ccv + 3.f * frac * cdv);
        float p = tanh_f(v + bf3E) * dx;
        // 16-lane butterfly via DPP (xor 1,2,4,8)
        p = DPP_ADD(p, 0xB1);    // quad_perm [1,0,3,2]
        p = DPP_ADD(p, 0x4E);    // quad_perm [2,3,0,1]
        p = DPP_ADD(p, 0x141);   // row_half_mirror
        p = DPP_ADD(p, 0x140);   // row_mirror

        // wave-uniform RK arithmetic; only c==0 writes
        float sa = AE[j][j] * p;
        #pragma unroll
        for (int m = 0; m < 5; ++m) if (m < j) sa = fmaf(AE[j][m], kprev[m], sa);
        float yn = fmaf(hstep, sa, yr);
        if (j == 5) yr = yn;
        if (c == 0) {
          if (j < 5) skr[j][sE] = p;
          syj_h[sE] = (half_t)yn;
          if (j == 5) syf[sE] = yn;
        }
      }
      __syncthreads();   // B3
    }
  }

  // final projection: out[b,63,:]
  if (w == 0) {
    const int oo = lane >> 3, kc = lane & 7;
    float a = 0.f;
    #pragma unroll
    for (int i = 0; i < 8; ++i) a += syf[kc * 8 + i] * sWr[oo * S_ + kc * 8 + i];
    a += __shfl_down(a, 4, 8);
    a += __shfl_down(a, 2, 8);
    a += __shfl_down(a, 1, 8);
    if (kc == 0) out[((size_t)b * T_ + (T_ - 1)) * O_ + oo] = a + sbr[oo];
  }
}

extern "C" void kernel_launch(void* const* d_in, const int* in_sizes, int n_in,
                              void* d_out, int out_size, void* d_ws, size_t ws_size,
                              hipStream_t stream) {
  const float* ts  = (const float*)d_in[0];
  const float* cd  = (const float*)d_in[1];
  const float* cc  = (const float*)d_in[2];
  const float* cb  = (const float*)d_in[3];
  const float* ca  = (const float*)d_in[4];
  const float* Wi1 = (const float*)d_in[5];
  const float* bi1 = (const float*)d_in[6];
  const float* Wi2 = (const float*)d_in[7];
  const float* bi2 = (const float*)d_in[8];
  const float* Wf1 = (const float*)d_in[9];
  const float* bf1 = (const float*)d_in[10];
  const float* Wf2 = (const float*)d_in[11];
  const float* bf2 = (const float*)d_in[12];
  const float* Wf3 = (const float*)d_in[13];
  const float* bf3 = (const float*)d_in[14];
  const float* Wr  = (const float*)d_in[15];
  const float* br  = (const float*)d_in[16];

  half_t* wsh = (half_t*)d_ws;
  hipLaunchKernelGGL(convert_kernel, dim3((WS_HALVES + 255) / 256), dim3(256), 0, stream,
                     Wf1, Wf2, Wf3, wsh);
  hipLaunchKernelGGL(cde_kernel_mfma, dim3(B_), dim3(NT), 0, stream,
                     ts, cd, cc, cb, ca, Wi1, bi1, Wi2, bi2,
                     bf1, bf2, bf3, Wr, br, wsh, (float*)d_out);
}

// Round 11
// 526.559 us; speedup vs baseline: 1.2325x; 1.2325x over previous
//
#include <hip/hip_runtime.h>
#include <math.h>

typedef _Float16 half_t;
typedef _Float16 half8_t __attribute__((ext_vector_type(8)));
typedef float float4_t __attribute__((ext_vector_type(4)));

#define T_ 64
#define B_ 256
#define D_ 16
#define S_ 64
#define H_ 128
#define O_ 8
#define NSTEP 63
#define NT 512

// ws layout (halves): Wf3 [1024][128] | Wf1 [128][64] | Wf2 [128][128], row-major fp16
#define W3_OFF 0
#define W1_OFF 131072
#define W2_OFF 139264
#define WS_HALVES 155648

#define MFMA16(a, b, c) __builtin_amdgcn_mfma_f32_16x16x32_f16(a, b, c, 0, 0, 0)

// DPP 16-lane butterfly add (VALU; replaces ds_bpermute-based __shfl_xor).
// Ladder validated for correctness in R10 (absmax unchanged).
#if __has_builtin(__builtin_amdgcn_mov_dpp)
#define DPP_ADD(x, ctrl) \
  ((x) + __int_as_float(__builtin_amdgcn_mov_dpp(__float_as_int(x), (ctrl), 0xF, 0xF, true)))
#else
#define DPP_ADD(x, ctrl) ((x) + __shfl_xor((x), (ctrl) == 0xB1 ? 1 : (ctrl) == 0x4E ? 2 : (ctrl) == 0x141 ? 4 : 8))
#endif

// AE[j] = coefficients on k[0..j] producing the NEXT stage input (j<5) or B_SOL (j==5)
__device__ constexpr float AE[6][6] = {
  {0.161f, 0.f, 0.f, 0.f, 0.f, 0.f},
  {-0.008480655492356989f, 0.335480655492357f, 0.f, 0.f, 0.f, 0.f},
  {2.8971530571054935f, -6.359448489975075f, 4.3622954328695815f, 0.f, 0.f, 0.f},
  {5.325864828439257f, -11.748883564062828f, 7.4955393428898365f, -0.09249506636175525f, 0.f, 0.f},
  {5.86145544294642f, -12.92096931784711f, 8.159367898576159f, -0.071584973281401f, -0.028269050394068383f, 0.f},
  {0.09646076681806523f, 0.01f, 0.4798896504144996f, 1.379008574103742f, -3.290069515436081f, 2.324710524099774f}
};
__device__ constexpr float CCn[6] = {0.f, 0.161f, 0.327f, 0.9f, 0.9800255409045097f, 1.f};

__device__ __forceinline__ float softplus_f(float x) {
  return fmaxf(x, 0.f) + __logf(1.f + __expf(-fabsf(x)));
}
__device__ __forceinline__ float tanh_f(float x) {
  float xc = fminf(fmaxf(x, -12.f), 12.f);
  float e = __expf(2.f * xc);
  return (e - 1.f) * __builtin_amdgcn_rcpf(e + 1.f);
}

// ---------------- prologue: fp32 -> fp16 weight conversion (row-major) ----------------
__global__ __launch_bounds__(256) void convert_kernel(
    const float* __restrict__ Wf1, const float* __restrict__ Wf2,
    const float* __restrict__ Wf3, half_t* __restrict__ wsh)
{
  int q = blockIdx.x * 256 + threadIdx.x;
  if (q < W1_OFF) wsh[q] = (half_t)Wf3[q];
  else if (q < W2_OFF) wsh[q] = (half_t)Wf1[q - W1_OFF];
  else if (q < WS_HALVES) wsh[q] = (half_t)Wf2[q - W2_OFF];
}

// ---------------- main kernel: R7 base (8 waves, all-persistent) + critical-path cuts ----------------
__global__ void __launch_bounds__(NT) __attribute__((amdgpu_waves_per_eu(2, 2)))
cde_kernel_mfma(
    const float* __restrict__ ts,
    const float* __restrict__ coeff_d,
    const float* __restrict__ coeff_c,
    const float* __restrict__ coeff_b,
    const float* __restrict__ coeff_a,
    const float* __restrict__ Wi1, const float* __restrict__ bi1,
    const float* __restrict__ Wi2, const float* __restrict__ bi2,
    const float* __restrict__ bf1, const float* __restrict__ bf2,
    const float* __restrict__ bf3,
    const float* __restrict__ Wr, const float* __restrict__ br,
    const half_t* __restrict__ wsh,
    float* __restrict__ out)
{
  __shared__ __align__(16) half_t syj_h[S_];
  __shared__ __align__(16) half_t sh1h[H_];
  __shared__ __align__(16) half_t sh2h[H_];
  __shared__ float syf[S_];
  __shared__ float sWr[O_ * S_];
  __shared__ float sbr[O_];
  __shared__ float sx0[D_];
  __shared__ float sini[H_];
  __shared__ float shs[T_];

  const int tid = threadIdx.x;
  const int b = blockIdx.x;
  const int w = tid >> 6;          // wave 0..7
  const int lane = tid & 63;
  const int q = lane >> 4;         // 16-lane row 0..3
  const int c = lane & 15;         // fragment column

  const half_t* __restrict__ w3p = wsh + W3_OFF;
  const half_t* __restrict__ w1p = wsh + W1_OFF;
  const half_t* __restrict__ w2p = wsh + W2_OFF;

  // ---- persistent B fragments (AGPR-resident; MFMA reads them natively) ----
  const int n1 = 16 * w + c;       // output column for h1/h2 tiles
  half8_t bW1[2], bW2[4], bW3[8][4];
  #pragma unroll
  for (int ks = 0; ks < 2; ++ks)
    bW1[ks] = *(const half8_t*)(w1p + n1 * S_ + ks * 32 + q * 8);
  #pragma unroll
  for (int ks = 0; ks < 4; ++ks)
    bW2[ks] = *(const half8_t*)(w2p + n1 * H_ + ks * 32 + q * 8);
  #pragma unroll
  for (int t = 0; t < 8; ++t) {
    const int r = 16 * (8 * w + t) + c;   // Wf3 row for this tile/col
    #pragma unroll
    for (int ks = 0; ks < 4; ++ks)
      bW3[t][ks] = *(const half8_t*)(w3p + (size_t)r * H_ + ks * 32 + q * 8);
  }
  const float bf1r = bf1[n1];
  const float bf2r = bf2[n1];
  // epilogue rows this lane keeps: s0 = 8w+2q, s1 = s0+1 (col c = d)
  const int s0 = 8 * w + 2 * q;
  const float bf3r0 = bf3[16 * s0 + c];
  const float bf3r1 = bf3[16 * (s0 + 1) + c];

  // ---- one-time staging + y0 ----
  if (tid < O_ * S_) sWr[tid] = Wr[tid];
  if (tid < O_) sbr[tid] = br[tid];
  if (tid < D_) sx0[tid] = coeff_a[(size_t)b * NSTEP * D_ + tid];
  if (tid < NSTEP) shs[tid] = ts[tid + 1] - ts[tid];
  __syncthreads();
  if (tid < H_) {
    float acc = bi1[tid];
    #pragma unroll
    for (int d = 0; d < D_; ++d) acc += sx0[d] * Wi1[tid * D_ + d];
    sini[tid] = softplus_f(acc);
  }
  __syncthreads();
  if (tid < S_) {
    float acc = bi2[tid];
    for (int h = 0; h < H_; ++h) acc += sini[h] * Wi2[tid * H_ + h];
    syf[tid] = acc;
  }
  __syncthreads();

  // RK state wave-uniform per 16-lane row: all lanes of row q track y[s0], y[s0+1]
  float yr0 = syf[s0];
  float yr1 = syf[s0 + 1];
  float kr0[6] = {0.f,0.f,0.f,0.f,0.f,0.f};
  float kr1[6] = {0.f,0.f,0.f,0.f,0.f,0.f};
  if (c == 0) {
    syj_h[s0] = (half_t)yr0;
    syj_h[s0 + 1] = (half_t)yr1;
  }
  __syncthreads();

  const float4_t Zv = {0.f, 0.f, 0.f, 0.f};

  // ---- time loop ----
  for (int t = 0; t < NSTEP; ++t) {
    const float hstep = shs[t];
    const size_t cidx = ((size_t)b * NSTEP + t) * D_ + c;
    const float cbv = coeff_b[cidx];
    const float ccv = coeff_c[cidx];
    const float cdv = coeff_d[cidx];

    #pragma unroll
    for (int j = 0; j < 6; ++j) {
      // ---- h1: yj @ Wf1^T (K=64), split accumulators ----
      {
        const half8_t* ap = (const half8_t*)syj_h;
        half8_t a0 = ap[q];           // k = q*8 ..
        half8_t a1 = ap[4 + q];       // k = 32 + q*8 ..
        float4_t acc0 = MFMA16(a0, bW1[0], Zv);
        float4_t acc1 = MFMA16(a1, bW1[1], Zv);
        if (q == 0) sh1h[n1] = (half_t)softplus_f(acc0[0] + acc1[0] + bf1r);
      }
      // projection of y_t overlapped here (wave 7, stage 0): syf stable until j==5
      if (w == 7 && j == 0) {
        const int oo = lane >> 3, kc = lane & 7;
        float a = 0.f;
        #pragma unroll
        for (int i = 0; i < 8; ++i) a += syf[kc * 8 + i] * sWr[oo * S_ + kc * 8 + i];
        a += __shfl_down(a, 4, 8);
        a += __shfl_down(a, 2, 8);
        a += __shfl_down(a, 1, 8);
        if (kc == 0) out[((size_t)b * T_ + t) * O_ + oo] = a + sbr[oo];
      }
      __syncthreads();   // B1

      // ---- h2: h1 @ Wf2^T (K=128), two independent 2-chains ----
      {
        const half8_t* ap = (const half8_t*)sh1h;
        half8_t a0 = ap[q], a1 = ap[4 + q], a2 = ap[8 + q], a3 = ap[12 + q];
        float4_t accA = MFMA16(a0, bW2[0], Zv);
        float4_t accB = MFMA16(a1, bW2[1], Zv);
        accA = MFMA16(a2, bW2[2], accA);
        accB = MFMA16(a3, bW2[3], accB);
        if (q == 0) sh2h[n1] = (half_t)softplus_f(accA[0] + accB[0] + bf2r);
      }
      __syncthreads();   // B2

      // ---- GEMV3: 8 tiles (interleaved independent chains) + epilogue + RK ----
      {
        const half8_t* ap = (const half8_t*)sh2h;
        half8_t a0 = ap[q], a1 = ap[4 + q], a2 = ap[8 + q], a3 = ap[12 + q];
        float4_t acc3[8];
        #pragma unroll
        for (int tt = 0; tt < 8; ++tt) acc3[tt] = MFMA16(a0, bW3[tt][0], Zv);
        #pragma unroll
        for (int tt = 0; tt < 8; ++tt) acc3[tt] = MFMA16(a1, bW3[tt][1], acc3[tt]);
        #pragma unroll
        for (int tt = 0; tt < 8; ++tt) acc3[tt] = MFMA16(a2, bW3[tt][2], acc3[tt]);
        #pragma unroll
        for (int tt = 0; tt < 8; ++tt) acc3[tt] = MFMA16(a3, bW3[tt][3], acc3[tt]);

        // quad q consumes tiles 2q, 2q+1
        float v0, v1;
        if (q == 0)      { v0 = acc3[0][0]; v1 = acc3[1][0]; }
        else if (q == 1) { v0 = acc3[2][0]; v1 = acc3[3][0]; }
        else if (q == 2) { v0 = acc3[4][0]; v1 = acc3[5][0]; }
        else             { v0 = acc3[6][0]; v1 = acc3[7][0]; }

        const float frac = CCn[j] * hstep;
        const float dx = cbv + frac * (2.f * ccv + 3.f * frac * cdv);
        float p0 = tanh_f(v0 + bf3r0) * dx;
        float p1 = tanh_f(v1 + bf3r1) * dx;
        // 16-lane butterfly via DPP (VALU, ~4cyc/step vs ~40 for ds_bpermute)
        p0 = DPP_ADD(p0, 0xB1);   p1 = DPP_ADD(p1, 0xB1);    // xor 1
        p0 = DPP_ADD(p0, 0x4E);   p1 = DPP_ADD(p1, 0x4E);    // xor 2
        p0 = DPP_ADD(p0, 0x141);  p1 = DPP_ADD(p1, 0x141);   // half-row mirror
        p0 = DPP_ADD(p0, 0x140);  p1 = DPP_ADD(p1, 0x140);   // row mirror

        // wave-uniform RK arithmetic (same register cost as divergent; shorter chain)
        kr0[j] = p0;
        kr1[j] = p1;
        float sa0 = AE[j][0] * kr0[0];
        float sa1 = AE[j][0] * kr1[0];
        #pragma unroll
        for (int m = 1; m < 6; ++m) if (m <= j) { sa0 = fmaf(AE[j][m], kr0[m], sa0); sa1 = fmaf(AE[j][m], kr1[m], sa1); }
        float yn0 = fmaf(hstep, sa0, yr0);
        float yn1 = fmaf(hstep, sa1, yr1);
        if (j == 5) { yr0 = yn0; yr1 = yn1; }
        if (c == 0) {
          syj_h[s0] = (half_t)yn0;
          syj_h[s0 + 1] = (half_t)yn1;
          if (j == 5) { syf[s0] = yn0; syf[s0 + 1] = yn1; }
        }
      }
      __syncthreads();   // B3
    }
  }

  // final projection: out[b,63,:]
  if (w == 7) {
    const int oo = lane >> 3, kc = lane & 7;
    float a = 0.f;
    #pragma unroll
    for (int i = 0; i < 8; ++i) a += syf[kc * 8 + i] * sWr[oo * S_ + kc * 8 + i];
    a += __shfl_down(a, 4, 8);
    a += __shfl_down(a, 2, 8);
    a += __shfl_down(a, 1, 8);
    if (kc == 0) out[((size_t)b * T_ + (T_ - 1)) * O_ + oo] = a + sbr[oo];
  }
}

extern "C" void kernel_launch(void* const* d_in, const int* in_sizes, int n_in,
                              void* d_out, int out_size, void* d_ws, size_t ws_size,
                              hipStream_t stream) {
  const float* ts  = (const float*)d_in[0];
  const float* cd  = (const float*)d_in[1];
  const float* cc  = (const float*)d_in[2];
  const float* cb  = (const float*)d_in[3];
  const float* ca  = (const float*)d_in[4];
  const float* Wi1 = (const float*)d_in[5];
  const float* bi1 = (const float*)d_in[6];
  const float* Wi2 = (const float*)d_in[7];
  const float* bi2 = (const float*)d_in[8];
  const float* Wf1 = (const float*)d_in[9];
  const float* bf1 = (const float*)d_in[10];
  const float* Wf2 = (const float*)d_in[11];
  const float* bf2 = (const float*)d_in[12];
  const float* Wf3 = (const float*)d_in[13];
  const float* bf3 = (const float*)d_in[14];
  const float* Wr  = (const float*)d_in[15];
  const float* br  = (const float*)d_in[16];

  half_t* wsh = (half_t*)d_ws;
  hipLaunchKernelGGL(convert_kernel, dim3((WS_HALVES + 255) / 256), dim3(256), 0, stream,
                     Wf1, Wf2, Wf3, wsh);
  hipLaunchKernelGGL(cde_kernel_mfma, dim3(B_), dim3(NT), 0, stream,
                     ts, cd, cc, cb, ca, Wi1, bi1, Wi2, bi2,
                     bf1, bf2, bf3, Wr, br, wsh, (float*)d_out);
}

// Round 12
// 504.838 us; speedup vs baseline: 1.2855x; 1.0430x over previous
//
#include <hip/hip_runtime.h>
#include <math.h>

typedef _Float16 half_t;
typedef _Float16 half2_t __attribute__((ext_vector_type(2)));
typedef _Float16 half8_t __attribute__((ext_vector_type(8)));
typedef float float4_t __attribute__((ext_vector_type(4)));

#define T_ 64
#define B_ 256
#define D_ 16
#define S_ 64
#define SP_ 68   // padded y-history row stride (floats) to break projection bank conflicts
#define H_ 128
#define O_ 8
#define NSTEP 63
#define NT 512

// ws layout (halves): Wf3 [1024][128] | Wf1 [128][64] | Wf2 [128][128], row-major fp16
#define W3_OFF 0
#define W1_OFF 131072
#define W2_OFF 139264
#define WS_HALVES 155648

#define MFMA16(a, b, c) __builtin_amdgcn_mfma_f32_16x16x32_f16(a, b, c, 0, 0, 0)

// DPP 16-lane butterfly add (VALU; validated R10/R11)
#if __has_builtin(__builtin_amdgcn_mov_dpp)
#define DPP_ADD(x, ctrl) \
  ((x) + __int_as_float(__builtin_amdgcn_mov_dpp(__float_as_int(x), (ctrl), 0xF, 0xF, true)))
#else
#define DPP_ADD(x, ctrl) ((x) + __shfl_xor((x), (ctrl) == 0xB1 ? 1 : (ctrl) == 0x4E ? 2 : (ctrl) == 0x141 ? 4 : 8))
#endif

// AE[j] = coefficients on k[0..j] producing the NEXT stage input (j<5) or B_SOL (j==5)
__device__ constexpr float AE[6][6] = {
  {0.161f, 0.f, 0.f, 0.f, 0.f, 0.f},
  {-0.008480655492356989f, 0.335480655492357f, 0.f, 0.f, 0.f, 0.f},
  {2.8971530571054935f, -6.359448489975075f, 4.3622954328695815f, 0.f, 0.f, 0.f},
  {5.325864828439257f, -11.748883564062828f, 7.4955393428898365f, -0.09249506636175525f, 0.f, 0.f},
  {5.86145544294642f, -12.92096931784711f, 8.159367898576159f, -0.071584973281401f, -0.028269050394068383f, 0.f},
  {0.09646076681806523f, 0.01f, 0.4798896504144996f, 1.379008574103742f, -3.290069515436081f, 2.324710524099774f}
};
__device__ constexpr float CCn[6] = {0.f, 0.161f, 0.327f, 0.9f, 0.9800255409045097f, 1.f};

__device__ __forceinline__ float softplus_f(float x) {
  return fmaxf(x, 0.f) + __logf(1.f + __expf(-fabsf(x)));
}
__device__ __forceinline__ float tanh_f(float x) {
  float xc = fminf(fmaxf(x, -12.f), 12.f);
  float e = __expf(2.f * xc);
  return (e - 1.f) * __builtin_amdgcn_rcpf(e + 1.f);
}

// ---------------- prologue: fp32 -> fp16 weight conversion (row-major) ----------------
__global__ __launch_bounds__(256) void convert_kernel(
    const float* __restrict__ Wf1, const float* __restrict__ Wf2,
    const float* __restrict__ Wf3, half_t* __restrict__ wsh)
{
  int q = blockIdx.x * 256 + threadIdx.x;
  if (q < W1_OFF) wsh[q] = (half_t)Wf3[q];
  else if (q < W2_OFF) wsh[q] = (half_t)Wf1[q - W1_OFF];
  else if (q < WS_HALVES) wsh[q] = (half_t)Wf2[q - W2_OFF];
}

// ---------------- main kernel ----------------
// 8 waves, 2/SIMD, all weights AGPR-persistent (R7/R11 lineage). Per stage:
// [h1: all waves] B1 [h2: all waves] B2 [G3 + DPP + wave-uniform RK] B3.
// y history kept in LDS; all 512 out-projections batched at kernel end.
__global__ void __launch_bounds__(NT) __attribute__((amdgpu_waves_per_eu(2, 2)))
cde_kernel_mfma(
    const float* __restrict__ ts,
    const float* __restrict__ coeff_d,
    const float* __restrict__ coeff_c,
    const float* __restrict__ coeff_b,
    const float* __restrict__ coeff_a,
    const float* __restrict__ Wi1, const float* __restrict__ bi1,
    const float* __restrict__ Wi2, const float* __restrict__ bi2,
    const float* __restrict__ bf1, const float* __restrict__ bf2,
    const float* __restrict__ bf3,
    const float* __restrict__ Wr, const float* __restrict__ br,
    const half_t* __restrict__ wsh,
    float* __restrict__ out)
{
  __shared__ __align__(16) half_t syj_h[S_];
  __shared__ __align__(16) half_t sh1h[H_];
  __shared__ __align__(16) half_t sh2h[H_];
  __shared__ __align__(16) float shist[T_][SP_];   // y history (padded rows)
  __shared__ float sWr[O_ * S_];
  __shared__ float sbr[O_];
  __shared__ float sx0[D_];
  __shared__ float sini[H_];
  __shared__ float shs[T_];

  const int tid = threadIdx.x;
  const int b = blockIdx.x;
  const int w = tid >> 6;          // wave 0..7
  const int lane = tid & 63;
  const int q = lane >> 4;         // 16-lane row 0..3
  const int c = lane & 15;         // fragment column

  const half_t* __restrict__ w3p = wsh + W3_OFF;
  const half_t* __restrict__ w1p = wsh + W1_OFF;
  const half_t* __restrict__ w2p = wsh + W2_OFF;

  // ---- persistent B fragments (AGPR-resident; MFMA reads them natively) ----
  const int n1 = 16 * w + c;       // output column for h1/h2 tiles
  half8_t bW1[2], bW2[4], bW3[8][4];
  #pragma unroll
  for (int ks = 0; ks < 2; ++ks)
    bW1[ks] = *(const half8_t*)(w1p + n1 * S_ + ks * 32 + q * 8);
  #pragma unroll
  for (int ks = 0; ks < 4; ++ks)
    bW2[ks] = *(const half8_t*)(w2p + n1 * H_ + ks * 32 + q * 8);
  #pragma unroll
  for (int t = 0; t < 8; ++t) {
    const int r = 16 * (8 * w + t) + c;   // Wf3 row for this tile/col
    #pragma unroll
    for (int ks = 0; ks < 4; ++ks)
      bW3[t][ks] = *(const half8_t*)(w3p + (size_t)r * H_ + ks * 32 + q * 8);
  }
  const float bf1r = bf1[n1];
  const float bf2r = bf2[n1];
  // epilogue rows this lane keeps: s0 = 8w+2q, s1 = s0+1 (col c = d)
  const int s0 = 8 * w + 2 * q;
  const float bf3r0 = bf3[16 * s0 + c];
  const float bf3r1 = bf3[16 * (s0 + 1) + c];

  // ---- one-time staging + y0 ----
  if (tid < O_ * S_) sWr[tid] = Wr[tid];
  if (tid < O_) sbr[tid] = br[tid];
  if (tid < D_) sx0[tid] = coeff_a[(size_t)b * NSTEP * D_ + tid];
  if (tid < NSTEP) shs[tid] = ts[tid + 1] - ts[tid];
  __syncthreads();
  if (tid < H_) {
    float acc = bi1[tid];
    #pragma unroll
    for (int d = 0; d < D_; ++d) acc += sx0[d] * Wi1[tid * D_ + d];
    sini[tid] = softplus_f(acc);
  }
  __syncthreads();
  if (tid < S_) {
    float acc = bi2[tid];
    for (int h = 0; h < H_; ++h) acc += sini[h] * Wi2[tid * H_ + h];
    shist[0][tid] = acc;
  }
  __syncthreads();

  // RK state wave-uniform per 16-lane row: all lanes of row q track y[s0], y[s0+1]
  float yr0 = shist[0][s0];
  float yr1 = shist[0][s0 + 1];
  float kr0[6] = {0.f,0.f,0.f,0.f,0.f,0.f};
  float kr1[6] = {0.f,0.f,0.f,0.f,0.f,0.f};
  if (c == 0) {
    half2_t p; p[0] = (half_t)yr0; p[1] = (half_t)yr1;
    *(half2_t*)(syj_h + s0) = p;
  }
  __syncthreads();

  const float4_t Zv = {0.f, 0.f, 0.f, 0.f};

  // ---- time loop ----
  for (int t = 0; t < NSTEP; ++t) {
    const float hstep = shs[t];
    const size_t cidx = ((size_t)b * NSTEP + t) * D_ + c;
    const float cbv = coeff_b[cidx];
    const float ccv = coeff_c[cidx];
    const float cdv = coeff_d[cidx];
    // precompute dx for all 6 stages (off the epilogue critical chain)
    float dxj[6];
    #pragma unroll
    for (int j = 0; j < 6; ++j) {
      const float frac = CCn[j] * hstep;
      dxj[j] = cbv + frac * (2.f * ccv + 3.f * frac * cdv);
    }

    #pragma unroll
    for (int j = 0; j < 6; ++j) {
      // ---- h1: yj @ Wf1^T (K=64), split accumulators ----
      {
        const half8_t* ap = (const half8_t*)syj_h;
        half8_t a0 = ap[q];           // k = q*8 ..
        half8_t a1 = ap[4 + q];       // k = 32 + q*8 ..
        float4_t acc0 = MFMA16(a0, bW1[0], Zv);
        float4_t acc1 = MFMA16(a1, bW1[1], Zv);
        if (q == 0) sh1h[n1] = (half_t)softplus_f(acc0[0] + acc1[0] + bf1r);
      }
      __syncthreads();   // B1

      // ---- h2: h1 @ Wf2^T (K=128), two independent 2-chains ----
      {
        const half8_t* ap = (const half8_t*)sh1h;
        half8_t a0 = ap[q], a1 = ap[4 + q], a2 = ap[8 + q], a3 = ap[12 + q];
        float4_t accA = MFMA16(a0, bW2[0], Zv);
        float4_t accB = MFMA16(a1, bW2[1], Zv);
        accA = MFMA16(a2, bW2[2], accA);
        accB = MFMA16(a3, bW2[3], accB);
        if (q == 0) sh2h[n1] = (half_t)softplus_f(accA[0] + accB[0] + bf2r);
      }
      __syncthreads();   // B2

      // ---- GEMV3: 8 tiles (independent chains) + epilogue + RK ----
      {
        const half8_t* ap = (const half8_t*)sh2h;
        half8_t a0 = ap[q], a1 = ap[4 + q], a2 = ap[8 + q], a3 = ap[12 + q];
        float4_t acc3[8];
        #pragma unroll
        for (int tt = 0; tt < 8; ++tt) acc3[tt] = MFMA16(a0, bW3[tt][0], Zv);
        #pragma unroll
        for (int tt = 0; tt < 8; ++tt) acc3[tt] = MFMA16(a1, bW3[tt][1], acc3[tt]);
        #pragma unroll
        for (int tt = 0; tt < 8; ++tt) acc3[tt] = MFMA16(a2, bW3[tt][2], acc3[tt]);
        #pragma unroll
        for (int tt = 0; tt < 8; ++tt) acc3[tt] = MFMA16(a3, bW3[tt][3], acc3[tt]);

        // quad q consumes tiles 2q, 2q+1
        float v0, v1;
        if (q == 0)      { v0 = acc3[0][0]; v1 = acc3[1][0]; }
        else if (q == 1) { v0 = acc3[2][0]; v1 = acc3[3][0]; }
        else if (q == 2) { v0 = acc3[4][0]; v1 = acc3[5][0]; }
        else             { v0 = acc3[6][0]; v1 = acc3[7][0]; }

        const float dx = dxj[j];
        float p0 = tanh_f(v0 + bf3r0) * dx;
        float p1 = tanh_f(v1 + bf3r1) * dx;
        // 16-lane butterfly via DPP
        p0 = DPP_ADD(p0, 0xB1);   p1 = DPP_ADD(p1, 0xB1);
        p0 = DPP_ADD(p0, 0x4E);   p1 = DPP_ADD(p1, 0x4E);
        p0 = DPP_ADD(p0, 0x141);  p1 = DPP_ADD(p1, 0x141);
        p0 = DPP_ADD(p0, 0x140);  p1 = DPP_ADD(p1, 0x140);

        // wave-uniform RK arithmetic
        kr0[j] = p0;
        kr1[j] = p1;
        float sa0 = AE[j][0] * kr0[0];
        float sa1 = AE[j][0] * kr1[0];
        #pragma unroll
        for (int m = 1; m < 6; ++m) if (m <= j) { sa0 = fmaf(AE[j][m], kr0[m], sa0); sa1 = fmaf(AE[j][m], kr1[m], sa1); }
        float yn0 = fmaf(hstep, sa0, yr0);
        float yn1 = fmaf(hstep, sa1, yr1);
        if (j == 5) { yr0 = yn0; yr1 = yn1; }
        if (c == 0) {
          half2_t p; p[0] = (half_t)yn0; p[1] = (half_t)yn1;
          *(half2_t*)(syj_h + s0) = p;
          if (j == 5) {
            float2 f; f.x = yn0; f.y = yn1;
            *(float2*)(&shist[t + 1][s0]) = f;
          }
        }
      }
      __syncthreads();   // B3
    }
  }

  // ---- batched projection epilogue: out[b, t, o] for all 64 t x 8 o ----
  __syncthreads();
  {
    const int tt = tid >> 3;       // 0..63
    const int oo = tid & 7;        // 0..7
    const float4* yp = (const float4*)(&shist[tt][0]);
    const float4* wp = (const float4*)(sWr + oo * S_);
    float a0 = 0.f, a1 = 0.f;
    #pragma unroll
    for (int i = 0; i < 16; i += 2) {
      float4 y0 = yp[i], w0 = wp[i];
      float4 y1 = yp[i + 1], w1 = wp[i + 1];
      a0 += y0.x * w0.x + y0.y * w0.y + y0.z * w0.z + y0.w * w0.w;
      a1 += y1.x * w1.x + y1.y * w1.y + y1.z * w1.z + y1.w * w1.w;
    }
    out[((size_t)b * T_ + tt) * O_ + oo] = a0 + a1 + sbr[oo];
  }
}

extern "C" void kernel_launch(void* const* d_in, const int* in_sizes, int n_in,
                              void* d_out, int out_size, void* d_ws, size_t ws_size,
                              hipStream_t stream) {
  const float* ts  = (const float*)d_in[0];
  const float* cd  = (const float*)d_in[1];
  const float* cc  = (const float*)d_in[2];
  const float* cb  = (const float*)d_in[3];
  const float* ca  = (const float*)d_in[4];
  const float* Wi1 = (const float*)d_in[5];
  const float* bi1 = (const float*)d_in[6];
  const float* Wi2 = (const float*)d_in[7];
  const float* bi2 = (const float*)d_in[8];
  const float* Wf1 = (const float*)d_in[9];
  const float* bf1 = (const float*)d_in[10];
  const float* Wf2 = (const float*)d_in[11];
  const float* bf2 = (const float*)d_in[12];
  const float* Wf3 = (const float*)d_in[13];
  const float* bf3 = (const float*)d_in[14];
  const float* Wr  = (const float*)d_in[15];
  const float* br  = (const float*)d_in[16];

  half_t* wsh = (half_t*)d_ws;
  hipLaunchKernelGGL(convert_kernel, dim3((WS_HALVES + 255) / 256), dim3(256), 0, stream,
                     Wf1, Wf2, Wf3, wsh);
  hipLaunchKernelGGL(cde_kernel_mfma, dim3(B_), dim3(NT), 0, stream,
                     ts, cd, cc, cb, ca, Wi1, bi1, Wi2, bi2,
                     bf1, bf2, bf3, Wr, br, wsh, (float*)d_out);
}